// Round 11
// baseline (440.786 us; speedup 1.0000x reference)
//
#include <hip/hip_runtime.h>
#include <hip/hip_fp16.h>

#define N_NODES 50000
#define N_EDGES 800000
#define D_INN 100
#define HID 128
#define N_GRAPHS 64
#define NBLK ((N_NODES + 255) / 256)   // 196
#define POOL_ROWS 128
#define POOL_BLOCKS ((N_NODES + POOL_ROWS - 1) / POOL_ROWS)  // 391

#define NBUCK 8
#define NODES_PER_BUCK (N_NODES / NBUCK)       // 6250
#define SCAT_BLOCKS 2048                        // 256 sub-blocks x 8 buckets
#define GEMM_BLOCKS 512
#define N_CHUNK (N_NODES / 16)                  // 3125

// 4-way column-split layout: buf[q][node][32 halfs], q = col/32
#define CB4_STRIDE  (N_NODES * 32)             // halfs per quarter (1.6M)
#define CB4_STRIDE2 (N_NODES * 16)             // half2 per quarter (800k)

typedef _Float16 f16x8 __attribute__((ext_vector_type(8)));
typedef _Float16 f16x4 __attribute__((ext_vector_type(4)));
typedef float f32x4 __attribute__((ext_vector_type(4)));

// ---------------- setup: deg=1, sums=0, W transposes to fp16 ----------------
__global__ __launch_bounds__(256) void k_setup(int* __restrict__ deg,
                                               float* __restrict__ sums,
                                               const float* __restrict__ W,
                                               const float* __restrict__ We,
                                               __half* __restrict__ Wt,
                                               __half* __restrict__ Wte) {
    int i = blockIdx.x * 256 + threadIdx.x;
    if (i < N_NODES) deg[i] = 1;
    if (i < N_GRAPHS * HID) sums[i] = 0.f;
    if (i < 3 * HID * HID) {
        int l = i >> 14, rem = i & 16383;
        int c = rem >> 7, k = rem & 127;
        Wt[(l << 14) + c * HID + k] = __float2half(W[(l << 14) + k * HID + c]);
    } else if (i < 4 * HID * HID) {
        int j = i - 3 * HID * HID;
        int c = j >> 7, k = j & 127;
        float v = (k < D_INN) ? We[k * HID + c] : 0.f;
        Wte[c * HID + k] = __float2half(v);
    }
}

// ---------------- degree: XCD-affine bucket-filtered atomics ----------------
__global__ __launch_bounds__(256) void k_deg(const int* __restrict__ dst,
                                             int* __restrict__ deg) {
    int b = blockIdx.x & (NBUCK - 1);
    int lo = b * NODES_PER_BUCK, hi = lo + NODES_PER_BUCK;
    int sub = blockIdx.x >> 3, nsub = gridDim.x >> 3;
    for (int e = sub * 256 + threadIdx.x; e < N_EDGES; e += nsub * 256) {
        int d = dst[e];
        if (d >= lo && d < hi) atomicAdd(&deg[d], 1);
    }
}

// ---------------- two-level scan: offsets = exclusive prefix of deg ----------------
__global__ __launch_bounds__(256) void k_scan1(const int* __restrict__ deg,
                                               int* __restrict__ incl,
                                               int* __restrict__ bsums) {
    __shared__ int sm[256];
    int i = blockIdx.x * 256 + threadIdx.x;
    int v = (i < N_NODES) ? deg[i] : 0;
    sm[threadIdx.x] = v;
    __syncthreads();
    for (int off = 1; off < 256; off <<= 1) {
        int t = (threadIdx.x >= off) ? sm[threadIdx.x - off] : 0;
        __syncthreads();
        sm[threadIdx.x] += t;
        __syncthreads();
    }
    if (i < N_NODES) incl[i] = sm[threadIdx.x];
    if (threadIdx.x == 255) bsums[blockIdx.x] = sm[255];
}

__global__ __launch_bounds__(256) void k_scan2(const int* __restrict__ bsums,
                                               int* __restrict__ boff) {
    __shared__ int sm[256];
    int v = (threadIdx.x < NBLK) ? bsums[threadIdx.x] : 0;
    sm[threadIdx.x] = v;
    __syncthreads();
    for (int off = 1; off < 256; off <<= 1) {
        int t = (threadIdx.x >= off) ? sm[threadIdx.x - off] : 0;
        __syncthreads();
        sm[threadIdx.x] += t;
        __syncthreads();
    }
    boff[threadIdx.x] = sm[threadIdx.x] - v;   // exclusive
}

// offsets[i+1]; self-loop at slot offsets[i] (no atomic); cursor=offsets[i]+1; dinv
__global__ void k_scan3(const int* __restrict__ incl, const int* __restrict__ boff,
                        const int* __restrict__ deg, int* __restrict__ offsets,
                        int* __restrict__ cursor, int* __restrict__ csr_src,
                        float* __restrict__ dinv) {
    int i = blockIdx.x * 256 + threadIdx.x;
    if (i < N_NODES) {
        int off1 = incl[i] + boff[blockIdx.x];
        offsets[i + 1] = off1;
        int dg = deg[i];
        int p0 = off1 - dg;
        csr_src[p0] = i;        // self loop first in segment
        cursor[i] = p0 + 1;
        dinv[i] = rsqrtf((float)dg);
    }
    if (i == 0) offsets[0] = 0;
}

// ---------------- CSR fill: XCD-affine bucket-filtered scatter ----------------
__global__ __launch_bounds__(256) void k_fill(const int* __restrict__ src,
                                              const int* __restrict__ dst,
                                              int* __restrict__ cursor,
                                              int* __restrict__ csr_src) {
    int b = blockIdx.x & (NBUCK - 1);
    int lo = b * NODES_PER_BUCK, hi = lo + NODES_PER_BUCK;
    int sub = blockIdx.x >> 3, nsub = gridDim.x >> 3;
    for (int e = sub * 256 + threadIdx.x; e < N_EDGES; e += nsub * 256) {
        int d = dst[e];
        if (d >= lo && d < hi) {
            int s = src[e];
            int p = atomicAdd(&cursor[d], 1);
            csr_src[p] = s;
        }
    }
}

// ---------------- encoder GEMM via MFMA, fp32 x -> CB4 fp16 out ----------------
// A-frag = W-tile (row=wcol), B-frag = node-tile (col=node); D col=node, rows=wcol.
// wave w's cols [w*32,w*32+32) = quarter w exactly -> CB4 stores stay 8B f16x4.
__global__ __launch_bounds__(256) void k_genc(const float* __restrict__ x,
                                              const _Float16* __restrict__ Wt,
                                              const float* __restrict__ bias,
                                              _Float16* __restrict__ out) {
    const int lane = threadIdx.x & 63;
    const int wave = threadIdx.x >> 6;
    const int l15  = lane & 15;
    const int lhi  = lane >> 4;
    f16x8 wf0[4], wf1[4];
#pragma unroll
    for (int ks = 0; ks < 4; ++ks) {
        wf0[ks] = *(const f16x8*)(Wt + (wave * 32 + l15) * HID + ks * 32 + lhi * 8);
        wf1[ks] = *(const f16x8*)(Wt + (wave * 32 + 16 + l15) * HID + ks * 32 + lhi * 8);
    }
    f32x4 bq0 = ((const f32x4*)bias)[wave * 8 + lhi];
    f32x4 bq1 = ((const f32x4*)bias)[wave * 8 + 4 + lhi];
    for (int chunk = blockIdx.x; chunk < N_CHUNK; chunk += gridDim.x) {
        int row0 = chunk * 16;
        const float* xr = x + (row0 + l15) * D_INN + lhi * 8;
        f16x8 nf[4];
#pragma unroll
        for (int ks = 0; ks < 3; ++ks) {
            float4 a = *(const float4*)(xr + ks * 32);
            float4 b = *(const float4*)(xr + ks * 32 + 4);
            f16x8 t;
            t[0] = (_Float16)a.x; t[1] = (_Float16)a.y;
            t[2] = (_Float16)a.z; t[3] = (_Float16)a.w;
            t[4] = (_Float16)b.x; t[5] = (_Float16)b.y;
            t[6] = (_Float16)b.z; t[7] = (_Float16)b.w;
            nf[ks] = t;
        }
        {
            f16x8 t;
            int kb = 96 + lhi * 8;
#pragma unroll
            for (int j = 0; j < 8; ++j)
                t[j] = (kb + j < D_INN) ? (_Float16)xr[96 + j] : (_Float16)0.f;
            nf[3] = t;
        }
        f32x4 acc0 = {0.f, 0.f, 0.f, 0.f};
        f32x4 acc1 = {0.f, 0.f, 0.f, 0.f};
#pragma unroll
        for (int ks = 0; ks < 4; ++ks) {
            acc0 = __builtin_amdgcn_mfma_f32_16x16x32_f16(wf0[ks], nf[ks], acc0, 0, 0, 0);
            acc1 = __builtin_amdgcn_mfma_f32_16x16x32_f16(wf1[ks], nf[ks], acc1, 0, 0, 0);
        }
        int node = row0 + l15;
        f16x4 o0, o1;
#pragma unroll
        for (int r = 0; r < 4; ++r) {
            o0[r] = (_Float16)(acc0[r] + bq0[r]);
            o1[r] = (_Float16)(acc1[r] + bq1[r]);
        }
        *(f16x4*)(out + wave * CB4_STRIDE + node * 32 + lhi * 4) = o0;
        *(f16x4*)(out + wave * CB4_STRIDE + node * 32 + 16 + lhi * 4) = o1;
    }
}

// ---------------- layer GEMM via MFMA: CB4 in -> CB4 out, dinv folded -------------
__global__ __launch_bounds__(256) void k_gemm(const _Float16* __restrict__ A,
                                              const _Float16* __restrict__ Wt,
                                              const float* __restrict__ dinv,
                                              _Float16* __restrict__ out) {
    const int lane = threadIdx.x & 63;
    const int wave = threadIdx.x >> 6;
    const int l15  = lane & 15;
    const int lhi  = lane >> 4;
    f16x8 wf0[4], wf1[4];
#pragma unroll
    for (int ks = 0; ks < 4; ++ks) {
        wf0[ks] = *(const f16x8*)(Wt + (wave * 32 + l15) * HID + ks * 32 + lhi * 8);
        wf1[ks] = *(const f16x8*)(Wt + (wave * 32 + 16 + l15) * HID + ks * 32 + lhi * 8);
    }
    for (int chunk = blockIdx.x; chunk < N_CHUNK; chunk += gridDim.x) {
        int row0 = chunk * 16;
        // K-block ks lives entirely in quarter ks of the CB4 layout
        const _Float16* Ar = A + (row0 + l15) * 32 + lhi * 8;
        f16x8 nf0 = *(const f16x8*)(Ar);
        f16x8 nf1 = *(const f16x8*)(Ar + CB4_STRIDE);
        f16x8 nf2 = *(const f16x8*)(Ar + 2 * CB4_STRIDE);
        f16x8 nf3 = *(const f16x8*)(Ar + 3 * CB4_STRIDE);
        f32x4 acc0 = {0.f, 0.f, 0.f, 0.f};
        f32x4 acc1 = {0.f, 0.f, 0.f, 0.f};
        acc0 = __builtin_amdgcn_mfma_f32_16x16x32_f16(wf0[0], nf0, acc0, 0, 0, 0);
        acc1 = __builtin_amdgcn_mfma_f32_16x16x32_f16(wf1[0], nf0, acc1, 0, 0, 0);
        acc0 = __builtin_amdgcn_mfma_f32_16x16x32_f16(wf0[1], nf1, acc0, 0, 0, 0);
        acc1 = __builtin_amdgcn_mfma_f32_16x16x32_f16(wf1[1], nf1, acc1, 0, 0, 0);
        acc0 = __builtin_amdgcn_mfma_f32_16x16x32_f16(wf0[2], nf2, acc0, 0, 0, 0);
        acc1 = __builtin_amdgcn_mfma_f32_16x16x32_f16(wf1[2], nf2, acc1, 0, 0, 0);
        acc0 = __builtin_amdgcn_mfma_f32_16x16x32_f16(wf0[3], nf3, acc0, 0, 0, 0);
        acc1 = __builtin_amdgcn_mfma_f32_16x16x32_f16(wf1[3], nf3, acc1, 0, 0, 0);
        int node = row0 + l15;
        float dr = dinv[node];
        f16x4 o0, o1;
#pragma unroll
        for (int r = 0; r < 4; ++r) {
            o0[r] = (_Float16)(acc0[r] * dr);
            o1[r] = (_Float16)(acc1[r] * dr);
        }
        *(f16x4*)(out + wave * CB4_STRIDE + node * 32 + lhi * 4) = o0;
        *(f16x4*)(out + wave * CB4_STRIDE + node * 32 + 16 + lhi * 4) = o1;
    }
}

// ---------------- aggregation: quarter-split, XCD-local gather ----------------
// quarter q = blockIdx&3 (XCD k serves quarter k%4; slice = 3.2MB < 4MB L2).
// One wave per node: 16 lanes x 4 edges in flight; 64B = 1 line per edge-quarter.
__global__ __launch_bounds__(256) void k_agg(const __half2* __restrict__ B2,
                                             const int* __restrict__ offsets,
                                             const int* __restrict__ csr_src,
                                             const float* __restrict__ dinv,
                                             const float* __restrict__ bias,
                                             __half2* __restrict__ A2) {
    int q = blockIdx.x & 3;
    int node = (blockIdx.x >> 2) * 4 + (threadIdx.x >> 6);
    int lane = threadIdx.x & 63;
    int col = lane & 15;         // half2 col within quarter
    int grp = lane >> 4;         // edge sub-slot 0..3
    const __half2* Bq = B2 + q * CB4_STRIDE2;
    int beg = offsets[node], end = offsets[node + 1];
    float ax0 = 0.f, ay0 = 0.f, ax1 = 0.f, ay1 = 0.f;
    int j = beg;
    while (j < end) {
        int take = end - j; if (take > 64) take = 64;
        int s_l = (lane < take) ? csr_src[j + lane] : 0;
        int t = 0;
        for (; t + 16 <= take; t += 16) {
            int sa = __shfl(s_l, t +  0 + grp);
            int sb = __shfl(s_l, t +  4 + grp);
            int sc = __shfl(s_l, t +  8 + grp);
            int sd = __shfl(s_l, t + 12 + grp);
            float2 fa = __half22float2(Bq[sa * 16 + col]);
            float2 fb = __half22float2(Bq[sb * 16 + col]);
            float2 fc = __half22float2(Bq[sc * 16 + col]);
            float2 fd = __half22float2(Bq[sd * 16 + col]);
            ax0 += fa.x; ay0 += fa.y;
            ax1 += fb.x; ay1 += fb.y;
            ax0 += fc.x; ay0 += fc.y;
            ax1 += fd.x; ay1 += fd.y;
        }
        for (; t < take; t += 4) {
            int idx = t + grp;
            int si = __shfl(s_l, idx < take ? idx : 0);
            if (idx < take) {
                float2 f = __half22float2(Bq[si * 16 + col]);
                ax0 += f.x; ay0 += f.y;
            }
        }
        j += take;
    }
    float ax = ax0 + ax1, ay = ay0 + ay1;
    ax += __shfl_xor(ax, 16); ay += __shfl_xor(ay, 16);
    ax += __shfl_xor(ax, 32); ay += __shfl_xor(ay, 32);
    if (lane < 16) {
        float dn = dinv[node];
        int cg = q * 32 + col * 2;
        float rx = fmaxf(fmaf(dn, ax, bias[cg]), 0.f);
        float ry = fmaxf(fmaf(dn, ay, bias[cg + 1]), 0.f);
        A2[q * CB4_STRIDE2 + node * 16 + col] = __floats2half2_rn(rx, ry);
    }
}

// ---------------- pooling stage 1 (CB4 input): per-chunk partials, atomic flush ----
__global__ __launch_bounds__(64) void k_pool_part(const __half2* __restrict__ A2,
                                                  const int* __restrict__ batch,
                                                  float* __restrict__ sums) {
    int base = blockIdx.x * POOL_ROWS;
    if (base >= N_NODES) return;
    int c2 = threadIdx.x;               // half2 col 0..63
    int q = c2 >> 4, off = c2 & 15;
    int cg = q * 32 + off * 2;
    const __half2* Aq = A2 + q * CB4_STRIDE2;
    int end = base + POOL_ROWS;
    if (end > N_NODES) end = N_NODES;
    float ax = 0.f, ay = 0.f;
    int g = batch[base];
    for (int n = base; n < end; ++n) {
        int bg = batch[n];
        if (bg != g) {
            atomicAdd(&sums[g * HID + cg], ax);
            atomicAdd(&sums[g * HID + cg + 1], ay);
            ax = 0.f; ay = 0.f;
            g = bg;
        }
        float2 f = __half22float2(Aq[n * 16 + off]);
        ax += f.x; ay += f.y;
    }
    atomicAdd(&sums[g * HID + cg], ax);
    atomicAdd(&sums[g * HID + cg + 1], ay);
}

// ---------------- head: out[g] = dot(sums[g]/cnt_g, W_reg) + b_reg ----------------
__global__ __launch_bounds__(128) void k_head(const float* __restrict__ sums,
                                              const int* __restrict__ batch,
                                              const float* __restrict__ W_reg,
                                              const float* __restrict__ b_reg,
                                              float* __restrict__ out) {
    int g = blockIdx.x;
    int lo = 0, hi = N_NODES;
    while (lo < hi) { int mid = (lo + hi) >> 1; if (batch[mid] < g) lo = mid + 1; else hi = mid; }
    int start = lo;
    hi = N_NODES;
    while (lo < hi) { int mid = (lo + hi) >> 1; if (batch[mid] < g + 1) lo = mid + 1; else hi = mid; }
    int end = lo;
    float cnt = (float)((end - start) > 0 ? (end - start) : 1);
    float v = (sums[g * HID + threadIdx.x] / cnt) * W_reg[threadIdx.x];
    for (int off = 32; off > 0; off >>= 1) v += __shfl_down(v, off);
    __shared__ float sm[2];
    if ((threadIdx.x & 63) == 0) sm[threadIdx.x >> 6] = v;
    __syncthreads();
    if (threadIdx.x == 0) out[g] = sm[0] + sm[1] + b_reg[0];
}

extern "C" void kernel_launch(void* const* d_in, const int* in_sizes, int n_in,
                              void* d_out, int out_size, void* d_ws, size_t ws_size,
                              hipStream_t stream) {
    const float* x      = (const float*)d_in[0];
    const int*   e_src  = (const int*)d_in[1];
    const int*   e_dst  = e_src + N_EDGES;
    const int*   batch  = (const int*)d_in[2];
    const float* W_enc  = (const float*)d_in[3];
    const float* b_enc  = (const float*)d_in[4];
    const float* gcn_W  = (const float*)d_in[5];
    const float* gcn_b  = (const float*)d_in[6];
    const float* W_reg  = (const float*)d_in[7];
    const float* b_reg  = (const float*)d_in[8];
    float* out = (float*)d_out;

    char* p = (char*)d_ws;
    auto carve = [&](size_t bytes) { char* q = p; p += (bytes + 255) & ~(size_t)255; return q; };
    __half* hA      = (__half*)carve(sizeof(__half) * N_NODES * HID);
    __half* msg     = (__half*)carve(sizeof(__half) * N_NODES * HID);
    __half* Wt      = (__half*)carve(sizeof(__half) * 3 * HID * HID);
    __half* Wte     = (__half*)carve(sizeof(__half) * HID * HID);
    int*    csr_src = (int*)   carve(sizeof(int)    * (N_EDGES + N_NODES));
    int*    deg     = (int*)   carve(sizeof(int)    * N_NODES);
    int*    cursor  = (int*)   carve(sizeof(int)    * N_NODES);
    int*    offsets = (int*)   carve(sizeof(int)    * (N_NODES + 1));
    int*    incl    = (int*)   carve(sizeof(int)    * N_NODES);
    int*    bsums   = (int*)   carve(sizeof(int)    * 256);
    int*    boff    = (int*)   carve(sizeof(int)    * 256);
    float*  dinv    = (float*) carve(sizeof(float)  * N_NODES);
    float*  sums    = (float*) carve(sizeof(float)  * N_GRAPHS * HID);

    k_setup<<<256, 256, 0, stream>>>(deg, sums, gcn_W, W_enc, Wt, Wte);
    k_deg<<<SCAT_BLOCKS, 256, 0, stream>>>(e_dst, deg);
    k_scan1<<<NBLK, 256, 0, stream>>>(deg, incl, bsums);
    k_scan2<<<1, 256, 0, stream>>>(bsums, boff);
    k_scan3<<<NBLK, 256, 0, stream>>>(incl, boff, deg, offsets, cursor, csr_src, dinv);
    k_fill<<<SCAT_BLOCKS, 256, 0, stream>>>(e_src, e_dst, cursor, csr_src);

    k_genc<<<GEMM_BLOCKS, 256, 0, stream>>>(
        x, (const _Float16*)Wte, b_enc, (_Float16*)hA);
    for (int l = 0; l < 3; ++l) {
        k_gemm<<<GEMM_BLOCKS, 256, 0, stream>>>(
            (const _Float16*)hA, (const _Float16*)(Wt + l * HID * HID), dinv,
            (_Float16*)msg);
        k_agg<<<N_NODES, 256, 0, stream>>>(
            (const __half2*)msg, offsets, csr_src, dinv, gcn_b + l * HID,
            (__half2*)hA);
    }
    k_pool_part<<<POOL_BLOCKS, 64, 0, stream>>>((const __half2*)hA, batch, sums);
    k_head<<<N_GRAPHS, 128, 0, stream>>>(sums, batch, W_reg, b_reg, out);
}

// Round 12
// 360.066 us; speedup vs baseline: 1.2242x; 1.2242x over previous
//
#include <hip/hip_runtime.h>
#include <hip/hip_fp16.h>

#define N_NODES 50000
#define N_EDGES 800000
#define D_INN 100
#define HID 128
#define N_GRAPHS 64
#define NBLK ((N_NODES + 255) / 256)   // 196
#define POOL_ROWS 128
#define POOL_BLOCKS ((N_NODES + POOL_ROWS - 1) / POOL_ROWS)  // 391

#define NBUCK 8
#define NODES_PER_BUCK (N_NODES / NBUCK)       // 6250
#define SCAT_BLOCKS 2048                        // 256 sub-blocks x 8 buckets
#define GEMM_BLOCKS 512
#define N_CHUNK (N_NODES / 16)                  // 3125

typedef _Float16 f16x8 __attribute__((ext_vector_type(8)));
typedef _Float16 f16x4 __attribute__((ext_vector_type(4)));
typedef float f32x4 __attribute__((ext_vector_type(4)));

// ---------------- setup: deg=1, sums=0, W transposes to fp16 ----------------
__global__ __launch_bounds__(256) void k_setup(int* __restrict__ deg,
                                               float* __restrict__ sums,
                                               const float* __restrict__ W,
                                               const float* __restrict__ We,
                                               __half* __restrict__ Wt,
                                               __half* __restrict__ Wte) {
    int i = blockIdx.x * 256 + threadIdx.x;
    if (i < N_NODES) deg[i] = 1;
    if (i < N_GRAPHS * HID) sums[i] = 0.f;
    if (i < 3 * HID * HID) {
        int l = i >> 14, rem = i & 16383;
        int c = rem >> 7, k = rem & 127;
        Wt[(l << 14) + c * HID + k] = __float2half(W[(l << 14) + k * HID + c]);
    } else if (i < 4 * HID * HID) {
        int j = i - 3 * HID * HID;
        int c = j >> 7, k = j & 127;
        float v = (k < D_INN) ? We[k * HID + c] : 0.f;
        Wte[c * HID + k] = __float2half(v);
    }
}

// ---------------- degree: XCD-affine bucket-filtered atomics ----------------
__global__ __launch_bounds__(256) void k_deg(const int* __restrict__ dst,
                                             int* __restrict__ deg) {
    int b = blockIdx.x & (NBUCK - 1);
    int lo = b * NODES_PER_BUCK, hi = lo + NODES_PER_BUCK;
    int sub = blockIdx.x >> 3, nsub = gridDim.x >> 3;
    for (int e = sub * 256 + threadIdx.x; e < N_EDGES; e += nsub * 256) {
        int d = dst[e];
        if (d >= lo && d < hi) atomicAdd(&deg[d], 1);
    }
}

// ---------------- two-level scan: offsets = exclusive prefix of deg ----------------
__global__ __launch_bounds__(256) void k_scan1(const int* __restrict__ deg,
                                               int* __restrict__ incl,
                                               int* __restrict__ bsums) {
    __shared__ int sm[256];
    int i = blockIdx.x * 256 + threadIdx.x;
    int v = (i < N_NODES) ? deg[i] : 0;
    sm[threadIdx.x] = v;
    __syncthreads();
    for (int off = 1; off < 256; off <<= 1) {
        int t = (threadIdx.x >= off) ? sm[threadIdx.x - off] : 0;
        __syncthreads();
        sm[threadIdx.x] += t;
        __syncthreads();
    }
    if (i < N_NODES) incl[i] = sm[threadIdx.x];
    if (threadIdx.x == 255) bsums[blockIdx.x] = sm[255];
}

__global__ __launch_bounds__(256) void k_scan2(const int* __restrict__ bsums,
                                               int* __restrict__ boff) {
    __shared__ int sm[256];
    int v = (threadIdx.x < NBLK) ? bsums[threadIdx.x] : 0;
    sm[threadIdx.x] = v;
    __syncthreads();
    for (int off = 1; off < 256; off <<= 1) {
        int t = (threadIdx.x >= off) ? sm[threadIdx.x - off] : 0;
        __syncthreads();
        sm[threadIdx.x] += t;
        __syncthreads();
    }
    boff[threadIdx.x] = sm[threadIdx.x] - v;   // exclusive
}

// offsets[i+1]; self-loop at slot offsets[i] (no atomic); cursor=offsets[i]+1; dinv
__global__ void k_scan3(const int* __restrict__ incl, const int* __restrict__ boff,
                        const int* __restrict__ deg, int* __restrict__ offsets,
                        int* __restrict__ cursor, int* __restrict__ csr_src,
                        float* __restrict__ dinv) {
    int i = blockIdx.x * 256 + threadIdx.x;
    if (i < N_NODES) {
        int off1 = incl[i] + boff[blockIdx.x];
        offsets[i + 1] = off1;
        int dg = deg[i];
        int p0 = off1 - dg;
        csr_src[p0] = i;        // self loop first in segment
        cursor[i] = p0 + 1;
        dinv[i] = rsqrtf((float)dg);
    }
    if (i == 0) offsets[0] = 0;
}

// ---------------- CSR fill: XCD-affine bucket-filtered scatter ----------------
__global__ __launch_bounds__(256) void k_fill(const int* __restrict__ src,
                                              const int* __restrict__ dst,
                                              int* __restrict__ cursor,
                                              int* __restrict__ csr_src) {
    int b = blockIdx.x & (NBUCK - 1);
    int lo = b * NODES_PER_BUCK, hi = lo + NODES_PER_BUCK;
    int sub = blockIdx.x >> 3, nsub = gridDim.x >> 3;
    for (int e = sub * 256 + threadIdx.x; e < N_EDGES; e += nsub * 256) {
        int d = dst[e];
        if (d >= lo && d < hi) {
            int s = src[e];
            int p = atomicAdd(&cursor[d], 1);
            csr_src[p] = s;
        }
    }
}

// ---------------- encoder GEMM via MFMA, reads fp32 x directly ----------------
// A-frag = W-tile (row=wcol), B-frag = node-tile (col=node) -> D[wcol][node]:
// lane holds node l15, wcols lhi*4+r -> 4 consecutive cols => 8B f16x4 stores.
__global__ __launch_bounds__(256) void k_genc(const float* __restrict__ x,
                                              const _Float16* __restrict__ Wt,
                                              const float* __restrict__ bias,
                                              _Float16* __restrict__ out) {
    const int lane = threadIdx.x & 63;
    const int wave = threadIdx.x >> 6;
    const int l15  = lane & 15;
    const int lhi  = lane >> 4;
    f16x8 wf0[4], wf1[4];
#pragma unroll
    for (int ks = 0; ks < 4; ++ks) {
        wf0[ks] = *(const f16x8*)(Wt + (wave * 32 + l15) * HID + ks * 32 + lhi * 8);
        wf1[ks] = *(const f16x8*)(Wt + (wave * 32 + 16 + l15) * HID + ks * 32 + lhi * 8);
    }
    f32x4 bq0 = ((const f32x4*)bias)[wave * 8 + lhi];
    f32x4 bq1 = ((const f32x4*)bias)[wave * 8 + 4 + lhi];
    for (int chunk = blockIdx.x; chunk < N_CHUNK; chunk += gridDim.x) {
        int row0 = chunk * 16;
        const float* xr = x + (row0 + l15) * D_INN + lhi * 8;
        f16x8 nf[4];
#pragma unroll
        for (int ks = 0; ks < 3; ++ks) {
            float4 a = *(const float4*)(xr + ks * 32);
            float4 b = *(const float4*)(xr + ks * 32 + 4);
            f16x8 t;
            t[0] = (_Float16)a.x; t[1] = (_Float16)a.y;
            t[2] = (_Float16)a.z; t[3] = (_Float16)a.w;
            t[4] = (_Float16)b.x; t[5] = (_Float16)b.y;
            t[6] = (_Float16)b.z; t[7] = (_Float16)b.w;
            nf[ks] = t;
        }
        {
            f16x8 t;
            int kb = 96 + lhi * 8;
#pragma unroll
            for (int j = 0; j < 8; ++j)
                t[j] = (kb + j < D_INN) ? (_Float16)xr[96 + j] : (_Float16)0.f;
            nf[3] = t;
        }
        f32x4 acc0 = {0.f, 0.f, 0.f, 0.f};
        f32x4 acc1 = {0.f, 0.f, 0.f, 0.f};
#pragma unroll
        for (int ks = 0; ks < 4; ++ks) {
            acc0 = __builtin_amdgcn_mfma_f32_16x16x32_f16(wf0[ks], nf[ks], acc0, 0, 0, 0);
            acc1 = __builtin_amdgcn_mfma_f32_16x16x32_f16(wf1[ks], nf[ks], acc1, 0, 0, 0);
        }
        int node = row0 + l15;
        f16x4 o0, o1;
#pragma unroll
        for (int r = 0; r < 4; ++r) {
            o0[r] = (_Float16)(acc0[r] + bq0[r]);
            o1[r] = (_Float16)(acc1[r] + bq1[r]);
        }
        *(f16x4*)(out + node * HID + wave * 32 + lhi * 4) = o0;
        *(f16x4*)(out + node * HID + wave * 32 + 16 + lhi * 4) = o1;
    }
}

// ---------------- layer GEMM via MFMA: out = fp16( dinv * (hA @ W) ) --------------
__global__ __launch_bounds__(256) void k_gemm(const _Float16* __restrict__ A,
                                              const _Float16* __restrict__ Wt,
                                              const float* __restrict__ dinv,
                                              _Float16* __restrict__ out) {
    const int lane = threadIdx.x & 63;
    const int wave = threadIdx.x >> 6;
    const int l15  = lane & 15;
    const int lhi  = lane >> 4;
    f16x8 wf0[4], wf1[4];
#pragma unroll
    for (int ks = 0; ks < 4; ++ks) {
        wf0[ks] = *(const f16x8*)(Wt + (wave * 32 + l15) * HID + ks * 32 + lhi * 8);
        wf1[ks] = *(const f16x8*)(Wt + (wave * 32 + 16 + l15) * HID + ks * 32 + lhi * 8);
    }
    for (int chunk = blockIdx.x; chunk < N_CHUNK; chunk += gridDim.x) {
        int row0 = chunk * 16;
        const _Float16* Ar = A + (row0 + l15) * HID + lhi * 8;
        f16x8 nf0 = *(const f16x8*)(Ar);
        f16x8 nf1 = *(const f16x8*)(Ar + 32);
        f16x8 nf2 = *(const f16x8*)(Ar + 64);
        f16x8 nf3 = *(const f16x8*)(Ar + 96);
        f32x4 acc0 = {0.f, 0.f, 0.f, 0.f};
        f32x4 acc1 = {0.f, 0.f, 0.f, 0.f};
        acc0 = __builtin_amdgcn_mfma_f32_16x16x32_f16(wf0[0], nf0, acc0, 0, 0, 0);
        acc1 = __builtin_amdgcn_mfma_f32_16x16x32_f16(wf1[0], nf0, acc1, 0, 0, 0);
        acc0 = __builtin_amdgcn_mfma_f32_16x16x32_f16(wf0[1], nf1, acc0, 0, 0, 0);
        acc1 = __builtin_amdgcn_mfma_f32_16x16x32_f16(wf1[1], nf1, acc1, 0, 0, 0);
        acc0 = __builtin_amdgcn_mfma_f32_16x16x32_f16(wf0[2], nf2, acc0, 0, 0, 0);
        acc1 = __builtin_amdgcn_mfma_f32_16x16x32_f16(wf1[2], nf2, acc1, 0, 0, 0);
        acc0 = __builtin_amdgcn_mfma_f32_16x16x32_f16(wf0[3], nf3, acc0, 0, 0, 0);
        acc1 = __builtin_amdgcn_mfma_f32_16x16x32_f16(wf1[3], nf3, acc1, 0, 0, 0);
        int node = row0 + l15;
        float dr = dinv[node];
        f16x4 o0, o1;
#pragma unroll
        for (int r = 0; r < 4; ++r) {
            o0[r] = (_Float16)(acc0[r] * dr);
            o1[r] = (_Float16)(acc1[r] * dr);
        }
        *(f16x4*)(out + node * HID + wave * 32 + lhi * 4) = o0;
        *(f16x4*)(out + node * HID + wave * 32 + 16 + lhi * 4) = o1;
    }
}

// ---------------- aggregation: hA[n] = fp16(relu(dinv[n] * sum_j msg[src_j] + b)) ----
// one wave per node, row-major gather (256B/edge coalesced), 8 gathers in flight.
__global__ __launch_bounds__(256) void k_agg(const __half* __restrict__ B,
                                             const int* __restrict__ offsets,
                                             const int* __restrict__ csr_src,
                                             const float* __restrict__ dinv,
                                             const float* __restrict__ bias,
                                             __half* __restrict__ A) {
    int node = (blockIdx.x * 256 + threadIdx.x) >> 6;
    int lane = threadIdx.x & 63;
    if (node >= N_NODES) return;
    int beg = offsets[node], end = offsets[node + 1];
    float ax0 = 0.f, ay0 = 0.f, ax1 = 0.f, ay1 = 0.f;
    const __half2* B2 = (const __half2*)B;
    int j = beg;
    while (j < end) {
        int take = end - j; if (take > 64) take = 64;
        int s_l = (lane < take) ? csr_src[j + lane] : 0;
        int t = 0;
        for (; t + 8 <= take; t += 8) {
            int s0 = __shfl(s_l, t + 0), s1 = __shfl(s_l, t + 1);
            int s2 = __shfl(s_l, t + 2), s3 = __shfl(s_l, t + 3);
            int s4 = __shfl(s_l, t + 4), s5 = __shfl(s_l, t + 5);
            int s6 = __shfl(s_l, t + 6), s7 = __shfl(s_l, t + 7);
            __half2 v0 = B2[s0 * 64 + lane];
            __half2 v1 = B2[s1 * 64 + lane];
            __half2 v2 = B2[s2 * 64 + lane];
            __half2 v3 = B2[s3 * 64 + lane];
            __half2 v4 = B2[s4 * 64 + lane];
            __half2 v5 = B2[s5 * 64 + lane];
            __half2 v6 = B2[s6 * 64 + lane];
            __half2 v7 = B2[s7 * 64 + lane];
            float2 f0 = __half22float2(v0);
            float2 f1 = __half22float2(v1);
            float2 f2 = __half22float2(v2);
            float2 f3 = __half22float2(v3);
            float2 f4 = __half22float2(v4);
            float2 f5 = __half22float2(v5);
            float2 f6 = __half22float2(v6);
            float2 f7 = __half22float2(v7);
            ax0 += f0.x; ay0 += f0.y;
            ax1 += f1.x; ay1 += f1.y;
            ax0 += f2.x; ay0 += f2.y;
            ax1 += f3.x; ay1 += f3.y;
            ax0 += f4.x; ay0 += f4.y;
            ax1 += f5.x; ay1 += f5.y;
            ax0 += f6.x; ay0 += f6.y;
            ax1 += f7.x; ay1 += f7.y;
        }
        for (; t + 4 <= take; t += 4) {
            int s0 = __shfl(s_l, t + 0), s1 = __shfl(s_l, t + 1);
            int s2 = __shfl(s_l, t + 2), s3 = __shfl(s_l, t + 3);
            float2 f0 = __half22float2(B2[s0 * 64 + lane]);
            float2 f1 = __half22float2(B2[s1 * 64 + lane]);
            float2 f2 = __half22float2(B2[s2 * 64 + lane]);
            float2 f3 = __half22float2(B2[s3 * 64 + lane]);
            ax0 += f0.x; ay0 += f0.y;
            ax1 += f1.x; ay1 += f1.y;
            ax0 += f2.x; ay0 += f2.y;
            ax1 += f3.x; ay1 += f3.y;
        }
        for (; t < take; ++t) {
            int s = __shfl(s_l, t);
            float2 f = __half22float2(B2[s * 64 + lane]);
            ax0 += f.x; ay0 += f.y;
        }
        j += take;
    }
    float dn = dinv[node];
    float2 b = ((const float2*)bias)[lane];
    float rx = fmaxf(fmaf(dn, ax0 + ax1, b.x), 0.f);
    float ry = fmaxf(fmaf(dn, ay0 + ay1, b.y), 0.f);
    ((__half2*)A)[node * 64 + lane] = __floats2half2_rn(rx, ry);
}

// ---------------- pooling stage 1: per-chunk partial sums, atomic flush ----------------
__global__ __launch_bounds__(64) void k_pool_part(const __half* __restrict__ A,
                                                  const int* __restrict__ batch,
                                                  float* __restrict__ sums) {
    int base = blockIdx.x * POOL_ROWS;
    if (base >= N_NODES) return;
    int c = threadIdx.x;           // half2 column index 0..63
    int end = base + POOL_ROWS;
    if (end > N_NODES) end = N_NODES;
    const __half2* A2 = (const __half2*)A;
    float ax = 0.f, ay = 0.f;
    int g = batch[base];
    for (int n = base; n < end; ++n) {
        int bg = batch[n];
        if (bg != g) {
            atomicAdd(&sums[g * HID + 2 * c], ax);
            atomicAdd(&sums[g * HID + 2 * c + 1], ay);
            ax = 0.f; ay = 0.f;
            g = bg;
        }
        float2 f = __half22float2(A2[n * 64 + c]);
        ax += f.x; ay += f.y;
    }
    atomicAdd(&sums[g * HID + 2 * c], ax);
    atomicAdd(&sums[g * HID + 2 * c + 1], ay);
}

// ---------------- head: out[g] = dot(sums[g]/cnt_g, W_reg) + b_reg ----------------
__global__ __launch_bounds__(128) void k_head(const float* __restrict__ sums,
                                              const int* __restrict__ batch,
                                              const float* __restrict__ W_reg,
                                              const float* __restrict__ b_reg,
                                              float* __restrict__ out) {
    int g = blockIdx.x;
    int lo = 0, hi = N_NODES;
    while (lo < hi) { int mid = (lo + hi) >> 1; if (batch[mid] < g) lo = mid + 1; else hi = mid; }
    int start = lo;
    hi = N_NODES;
    while (lo < hi) { int mid = (lo + hi) >> 1; if (batch[mid] < g + 1) lo = mid + 1; else hi = mid; }
    int end = lo;
    float cnt = (float)((end - start) > 0 ? (end - start) : 1);
    float v = (sums[g * HID + threadIdx.x] / cnt) * W_reg[threadIdx.x];
    for (int off = 32; off > 0; off >>= 1) v += __shfl_down(v, off);
    __shared__ float sm[2];
    if ((threadIdx.x & 63) == 0) sm[threadIdx.x >> 6] = v;
    __syncthreads();
    if (threadIdx.x == 0) out[g] = sm[0] + sm[1] + b_reg[0];
}

extern "C" void kernel_launch(void* const* d_in, const int* in_sizes, int n_in,
                              void* d_out, int out_size, void* d_ws, size_t ws_size,
                              hipStream_t stream) {
    const float* x      = (const float*)d_in[0];
    const int*   e_src  = (const int*)d_in[1];
    const int*   e_dst  = e_src + N_EDGES;
    const int*   batch  = (const int*)d_in[2];
    const float* W_enc  = (const float*)d_in[3];
    const float* b_enc  = (const float*)d_in[4];
    const float* gcn_W  = (const float*)d_in[5];
    const float* gcn_b  = (const float*)d_in[6];
    const float* W_reg  = (const float*)d_in[7];
    const float* b_reg  = (const float*)d_in[8];
    float* out = (float*)d_out;

    char* p = (char*)d_ws;
    auto carve = [&](size_t bytes) { char* q = p; p += (bytes + 255) & ~(size_t)255; return q; };
    __half* hA      = (__half*)carve(sizeof(__half) * N_NODES * HID);
    __half* msg     = (__half*)carve(sizeof(__half) * N_NODES * HID);
    __half* Wt      = (__half*)carve(sizeof(__half) * 3 * HID * HID);
    __half* Wte     = (__half*)carve(sizeof(__half) * HID * HID);
    int*    csr_src = (int*)   carve(sizeof(int)    * (N_EDGES + N_NODES));
    int*    deg     = (int*)   carve(sizeof(int)    * N_NODES);
    int*    cursor  = (int*)   carve(sizeof(int)    * N_NODES);
    int*    offsets = (int*)   carve(sizeof(int)    * (N_NODES + 1));
    int*    incl    = (int*)   carve(sizeof(int)    * N_NODES);
    int*    bsums   = (int*)   carve(sizeof(int)    * 256);
    int*    boff    = (int*)   carve(sizeof(int)    * 256);
    float*  dinv    = (float*) carve(sizeof(float)  * N_NODES);
    float*  sums    = (float*) carve(sizeof(float)  * N_GRAPHS * HID);

    k_setup<<<256, 256, 0, stream>>>(deg, sums, gcn_W, W_enc, Wt, Wte);
    k_deg<<<SCAT_BLOCKS, 256, 0, stream>>>(e_dst, deg);
    k_scan1<<<NBLK, 256, 0, stream>>>(deg, incl, bsums);
    k_scan2<<<1, 256, 0, stream>>>(bsums, boff);
    k_scan3<<<NBLK, 256, 0, stream>>>(incl, boff, deg, offsets, cursor, csr_src, dinv);
    k_fill<<<SCAT_BLOCKS, 256, 0, stream>>>(e_src, e_dst, cursor, csr_src);

    k_genc<<<GEMM_BLOCKS, 256, 0, stream>>>(
        x, (const _Float16*)Wte, b_enc, (_Float16*)hA);
    for (int l = 0; l < 3; ++l) {
        k_gemm<<<GEMM_BLOCKS, 256, 0, stream>>>(
            (const _Float16*)hA, (const _Float16*)(Wt + l * HID * HID), dinv,
            (_Float16*)msg);
        k_agg<<<(N_NODES * 64 + 255) / 256, 256, 0, stream>>>(
            msg, offsets, csr_src, dinv, gcn_b + l * HID, hA);
    }
    k_pool_part<<<POOL_BLOCKS, 64, 0, stream>>>(hA, batch, sums);
    k_head<<<N_GRAPHS, 128, 0, stream>>>(sums, batch, W_reg, b_reg, out);
}